// Round 1
// baseline (1390.441 us; speedup 1.0000x reference)
//
#include <hip/hip_runtime.h>

#define NPIX 9216
#define NL   21
#define QP   24
#define WW   96
#define CH   32
#define L2E  1.44269504088896340736f

__device__ __forceinline__ float fexp2(float x) { return __builtin_amdgcn_exp2f(x); }

// ---------- prep: bilateral features (both sides) + analytic spatial norm ----------
__global__ __launch_bounds__(256) void featK(const float* __restrict__ img,
                                             float* __restrict__ Fi, float* __restrict__ Fj,
                                             float* __restrict__ norm_s) {
    int i = blockIdx.x * 256 + threadIdx.x;
    if (i >= NPIX) return;
    int y = i / WW, x = i - y * WW;
    float f0 = (float)x * (1.0f / 160.0f);
    float f1 = (float)y * (1.0f / 160.0f);
    float f2 = img[0 * NPIX + i] * (1.0f / 3.0f);
    float f3 = img[1 * NPIX + i] * (1.0f / 3.0f);
    float f4 = img[2 * NPIX + i] * (1.0f / 3.0f);
    float st = 0.5f * (f0*f0 + f1*f1 + f2*f2 + f3*f3 + f4*f4) * L2E;
    float* a = Fi + (size_t)i * 8;
    float* b = Fj + (size_t)i * 8;
    a[0]=f0; a[1]=f1; a[2]=f2; a[3]=f3; a[4]=f4; a[5]=st; a[6]=0.f; a[7]=0.f;
    b[0]=f0*L2E; b[1]=f1*L2E; b[2]=f2*L2E; b[3]=f3*L2E; b[4]=f4*L2E; b[5]=st; b[6]=0.f; b[7]=0.f;
    // spatial (gamma=3) row-sum, exactly separable: sum_j Ks[i,j] = sx * sy
    const float cs = (-0.5f / 9.0f) * L2E;
    float sx = 0.f, sy = 0.f;
    for (int t = 0; t < WW; t++) {
        float dx = (float)(x - t); sx += fexp2(cs * dx * dx);
        float dy = (float)(y - t); sy += fexp2(cs * dy * dy);
    }
    norm_s[i] = 1.0f / (sx * sy + 1e-8f);
}

// ---------- fold 21x21 matrices: Ms = C @ Ws, Mb = C @ Wb ----------
__global__ __launch_bounds__(448) void matK(const float* __restrict__ Cm, const float* __restrict__ Wsm,
                                            const float* __restrict__ Wbm,
                                            float* __restrict__ Ms, float* __restrict__ Mb) {
    int t = threadIdx.x;
    if (t >= NL * NL) return;
    int l = t / NL, p = t - l * NL;
    float a = 0.f, b = 0.f;
    for (int m = 0; m < NL; m++) {
        float c = Cm[l * NL + m];
        a = fmaf(c, Wsm[m * NL + p], a);
        b = fmaf(c, Wbm[m * NL + p], b);
    }
    Ms[t] = a; Mb[t] = b;
}

// ---------- softmax over labels, write label-major (Qlm) and pixel-major (Qt) ----------
__global__ __launch_bounds__(256) void softmaxK(const float* __restrict__ cur,
                                                float* __restrict__ Qt, float* __restrict__ Qlm) {
    int i = blockIdx.x * 256 + threadIdx.x;
    if (i >= NPIX) return;
    float v[NL]; float m = -1e30f;
    #pragma unroll
    for (int l = 0; l < NL; l++) { v[l] = cur[l * NPIX + i]; m = fmaxf(m, v[l]); }
    float s = 0.f;
    #pragma unroll
    for (int l = 0; l < NL; l++) { v[l] = fexp2((v[l] - m) * L2E); s += v[l]; }
    float inv = 1.0f / s;
    #pragma unroll
    for (int l = 0; l < NL; l++) {
        float q = v[l] * inv;
        Qlm[l * NPIX + i] = q;
        Qt[(size_t)i * QP + l] = q;
    }
}

// ---------- spatial filtering: exact separable Gaussian, x-pass then y-pass ----------
__global__ __launch_bounds__(256) void spatX(const float* __restrict__ Qlm, float* __restrict__ S1) {
    int tid = blockIdx.x * 256 + threadIdx.x;   // NL*NPIX exact
    int l = tid / NPIX, rem = tid - l * NPIX;
    int y = rem / WW, x1 = rem - y * WW;
    const float cs = (-0.5f / 9.0f) * L2E;
    const float* row = Qlm + l * NPIX + y * WW;
    float acc = 0.f;
    for (int x2 = 0; x2 < WW; x2++) {
        float d = (float)(x1 - x2);
        acc = fmaf(fexp2(cs * d * d), row[x2], acc);
    }
    S1[tid] = acc;
}

__global__ __launch_bounds__(256) void spatY(const float* __restrict__ S1, const float* __restrict__ norm_s,
                                             float* __restrict__ Sp) {
    int tid = blockIdx.x * 256 + threadIdx.x;
    int l = tid / NPIX, rem = tid - l * NPIX;
    int y1 = rem / WW, x = rem - y1 * WW;
    const float cs = (-0.5f / 9.0f) * L2E;
    float acc = 0.f;
    for (int y2 = 0; y2 < WW; y2++) {
        float d = (float)(y1 - y2);
        acc = fmaf(fexp2(cs * d * d), S1[l * NPIX + y2 * WW + x], acc);
    }
    Sp[tid] = acc * norm_s[rem];
}

// ---------- bilateral: out[l,i] = sum_j exp2(fi.fj' - si - sj) q[l,j], fused norm row ----------
// block: 256 threads, 2 pixels each (i0, i0+256) -> 512-pixel i-tile; blockIdx.y = j-chunk
__global__ __launch_bounds__(256) void bilatK(const float* __restrict__ Qt, const float* __restrict__ Fi,
                                              const float* __restrict__ Fj,
                                              float* __restrict__ part, int njc) {
    __shared__ __align__(16) float sQ[CH * QP];   // 3 KB
    __shared__ __align__(16) float sF[CH * 8];    // 1 KB
    int t = threadIdx.x;
    int i0 = blockIdx.x * 512 + t;
    int jc = blockIdx.y;

    float4 fA0 = *reinterpret_cast<const float4*>(Fi + (size_t)i0 * 8);
    float2 fB0 = *reinterpret_cast<const float2*>(Fi + (size_t)i0 * 8 + 4);
    float4 fA1 = *reinterpret_cast<const float4*>(Fi + (size_t)(i0 + 256) * 8);
    float2 fB1 = *reinterpret_cast<const float2*>(Fi + (size_t)(i0 + 256) * 8 + 4);

    float acc0[NL], acc1[NL], s0 = 0.f, s1 = 0.f;
    #pragma unroll
    for (int l = 0; l < NL; l++) { acc0[l] = 0.f; acc1[l] = 0.f; }

    int jbeg = jc * njc;
    for (int jb = jbeg; jb < jbeg + njc; jb += CH) {
        __syncthreads();
        if (t < 192) reinterpret_cast<float4*>(sQ)[t]       = reinterpret_cast<const float4*>(Qt + (size_t)jb * QP)[t];
        else         reinterpret_cast<float4*>(sF)[t - 192] = reinterpret_cast<const float4*>(Fj + (size_t)jb * 8)[t - 192];
        __syncthreads();
        #pragma unroll 4
        for (int j = 0; j < CH; j++) {
            float4 fa = *reinterpret_cast<const float4*>(sF + j * 8);
            float2 fb = *reinterpret_cast<const float2*>(sF + j * 8 + 4);
            float b0 = -(fB0.y + fb.y);
            float b1 = -(fB1.y + fb.y);
            b0 = fmaf(fa.x, fA0.x, b0);  b1 = fmaf(fa.x, fA1.x, b1);
            b0 = fmaf(fa.y, fA0.y, b0);  b1 = fmaf(fa.y, fA1.y, b1);
            b0 = fmaf(fa.z, fA0.z, b0);  b1 = fmaf(fa.z, fA1.z, b1);
            b0 = fmaf(fa.w, fA0.w, b0);  b1 = fmaf(fa.w, fA1.w, b1);
            b0 = fmaf(fb.x, fB0.x, b0);  b1 = fmaf(fb.x, fB1.x, b1);
            float k0 = fexp2(b0), k1 = fexp2(b1);
            s0 += k0; s1 += k1;
            const float* qr = sQ + j * QP;
            #pragma unroll
            for (int l = 0; l < NL; l++) {
                float q = qr[l];
                acc0[l] = fmaf(k0, q, acc0[l]);
                acc1[l] = fmaf(k1, q, acc1[l]);
            }
        }
    }
    float* p = part + (size_t)jc * 22 * NPIX + i0;
    #pragma unroll
    for (int l = 0; l < NL; l++) {
        p[(size_t)l * NPIX]       = acc0[l];
        p[(size_t)l * NPIX + 256] = acc1[l];
    }
    p[(size_t)21 * NPIX] = s0;
    p[(size_t)21 * NPIX + 256] = s1;
}

// ---------- reduce j-chunks + apply bilateral norm ----------
__global__ __launch_bounds__(256) void bredK(const float* __restrict__ part, float* __restrict__ Bl, int js) {
    int i = blockIdx.x * 256 + threadIdx.x;
    if (i >= NPIX) return;
    float s = 1e-8f;
    for (int jc = 0; jc < js; jc++) s += part[((size_t)jc * 22 + 21) * NPIX + i];
    float inv = 1.0f / s;
    for (int l = 0; l < NL; l++) {
        float a = 0.f;
        for (int jc = 0; jc < js; jc++) a += part[((size_t)jc * 22 + l) * NPIX + i];
        Bl[l * NPIX + i] = a * inv;
    }
}

// ---------- combine: cur = Ms@Sp + Mb@Bl + unary ----------
__global__ __launch_bounds__(256) void combK(const float* __restrict__ Sp, const float* __restrict__ Bl,
                                             const float* __restrict__ Ms, const float* __restrict__ Mb,
                                             const float* __restrict__ unary, float* __restrict__ outp) {
    __shared__ float sMs[NL * NL], sMb[NL * NL];
    int t = threadIdx.x;
    for (int k = t; k < NL * NL; k += 256) { sMs[k] = Ms[k]; sMb[k] = Mb[k]; }
    __syncthreads();
    int i = blockIdx.x * 256 + t;
    if (i >= NPIX) return;
    float sp[NL], bl[NL];
    #pragma unroll
    for (int p = 0; p < NL; p++) { sp[p] = Sp[p * NPIX + i]; bl[p] = Bl[p * NPIX + i]; }
    for (int l = 0; l < NL; l++) {
        float a = unary[l * NPIX + i];
        #pragma unroll
        for (int p = 0; p < NL; p++) {
            a = fmaf(sMs[l * NL + p], sp[p], a);
            a = fmaf(sMb[l * NL + p], bl[p], a);
        }
        outp[l * NPIX + i] = a;
    }
}

extern "C" void kernel_launch(void* const* d_in, const int* in_sizes, int n_in,
                              void* d_out, int out_size, void* d_ws, size_t ws_size,
                              hipStream_t stream) {
    const float* img   = (const float*)d_in[0];
    const float* logit = (const float*)d_in[1];
    const float* Wsm   = (const float*)d_in[2];
    const float* Wbm   = (const float*)d_in[3];
    const float* Cm    = (const float*)d_in[4];
    float* out = (float*)d_out;
    float* ws  = (float*)d_ws;

    // workspace layout (floats)
    float* Fi     = ws;                          // N*8
    float* Fj     = Fi + NPIX * 8;               // N*8
    float* Qt     = Fj + NPIX * 8;               // N*24
    float* Qlm    = Qt + (size_t)NPIX * QP;      // L*N
    float* S1     = Qlm + NL * NPIX;             // L*N
    float* Sp     = S1 + NL * NPIX;              // L*N
    float* Bl     = Sp + NL * NPIX;              // L*N
    float* norm_s = Bl + NL * NPIX;              // N
    float* Ms     = norm_s + NPIX;               // 441
    float* Mb     = Ms + 441;                    // 441
    float* part   = ws + 1152896;                // js*22*N (16B aligned)

    size_t baseB = 1152896ull * sizeof(float);
    int js = 32;
    while (js > 1 && baseB + (size_t)js * 22 * NPIX * sizeof(float) > ws_size) js >>= 1;
    int njc = NPIX / js;

    featK<<<36, 256, 0, stream>>>(img, Fi, Fj, norm_s);
    matK<<<1, 448, 0, stream>>>(Cm, Wsm, Wbm, Ms, Mb);
    for (int it = 0; it < 5; ++it) {
        const float* cur = (it == 0) ? logit : out;
        softmaxK<<<36, 256, 0, stream>>>(cur, Qt, Qlm);
        spatX<<<756, 256, 0, stream>>>(Qlm, S1);
        spatY<<<756, 256, 0, stream>>>(S1, norm_s, Sp);
        bilatK<<<dim3(18, js), 256, 0, stream>>>(Qt, Fi, Fj, part, njc);
        bredK<<<36, 256, 0, stream>>>(part, Bl, js);
        combK<<<36, 256, 0, stream>>>(Sp, Bl, Ms, Mb, logit, out);
    }
}

// Round 2
// 590.447 us; speedup vs baseline: 2.3549x; 2.3549x over previous
//
#include <hip/hip_runtime.h>

#define NPIX 9216
#define NL   21
#define QP   24
#define WW   96
#define CH   32
#define L2E  1.44269504088896340736f

__device__ __forceinline__ float fexp2(float x) { return __builtin_amdgcn_exp2f(x); }

// ---------- prep: bilateral features (both sides) + analytic spatial norm ----------
__global__ __launch_bounds__(256) void featK(const float* __restrict__ img,
                                             float* __restrict__ Fi, float* __restrict__ Fj,
                                             float* __restrict__ norm_s) {
    int i = blockIdx.x * 256 + threadIdx.x;
    if (i >= NPIX) return;
    int y = i / WW, x = i - y * WW;
    float f0 = (float)x * (1.0f / 160.0f);
    float f1 = (float)y * (1.0f / 160.0f);
    float f2 = img[0 * NPIX + i] * (1.0f / 3.0f);
    float f3 = img[1 * NPIX + i] * (1.0f / 3.0f);
    float f4 = img[2 * NPIX + i] * (1.0f / 3.0f);
    float st = 0.5f * (f0*f0 + f1*f1 + f2*f2 + f3*f3 + f4*f4) * L2E;
    float* a = Fi + (size_t)i * 8;
    float* b = Fj + (size_t)i * 8;
    a[0]=f0; a[1]=f1; a[2]=f2; a[3]=f3; a[4]=f4; a[5]=st; a[6]=0.f; a[7]=0.f;
    b[0]=f0*L2E; b[1]=f1*L2E; b[2]=f2*L2E; b[3]=f3*L2E; b[4]=f4*L2E; b[5]=st; b[6]=0.f; b[7]=0.f;
    // spatial (gamma=3) row-sum, exactly separable: sum_j Ks[i,j] = sx * sy
    const float cs = (-0.5f / 9.0f) * L2E;
    float sx = 0.f, sy = 0.f;
    for (int t = 0; t < WW; t++) {
        float dx = (float)(x - t); sx += fexp2(cs * dx * dx);
        float dy = (float)(y - t); sy += fexp2(cs * dy * dy);
    }
    norm_s[i] = 1.0f / (sx * sy + 1e-8f);
}

// ---------- fold 21x21 matrices: Ms = C @ Ws, Mb = C @ Wb ----------
__global__ __launch_bounds__(448) void matK(const float* __restrict__ Cm, const float* __restrict__ Wsm,
                                            const float* __restrict__ Wbm,
                                            float* __restrict__ Ms, float* __restrict__ Mb) {
    int t = threadIdx.x;
    if (t >= NL * NL) return;
    int l = t / NL, p = t - l * NL;
    float a = 0.f, b = 0.f;
    for (int m = 0; m < NL; m++) {
        float c = Cm[l * NL + m];
        a = fmaf(c, Wsm[m * NL + p], a);
        b = fmaf(c, Wbm[m * NL + p], b);
    }
    Ms[t] = a; Mb[t] = b;
}

// ---------- softmax over labels, write label-major (Qlm) and pixel-major (Qt) ----------
__global__ __launch_bounds__(256) void softmaxK(const float* __restrict__ cur,
                                                float* __restrict__ Qt, float* __restrict__ Qlm) {
    int i = blockIdx.x * 256 + threadIdx.x;
    if (i >= NPIX) return;
    float v[NL]; float m = -1e30f;
    #pragma unroll
    for (int l = 0; l < NL; l++) { v[l] = cur[l * NPIX + i]; m = fmaxf(m, v[l]); }
    float s = 0.f;
    #pragma unroll
    for (int l = 0; l < NL; l++) { v[l] = fexp2((v[l] - m) * L2E); s += v[l]; }
    float inv = 1.0f / s;
    #pragma unroll
    for (int l = 0; l < NL; l++) {
        float q = v[l] * inv;
        Qlm[l * NPIX + i] = q;
        Qt[(size_t)i * QP + l] = q;
    }
}

// ---------- spatial filtering: exact separable Gaussian, x-pass then y-pass ----------
__global__ __launch_bounds__(256) void spatX(const float* __restrict__ Qlm, float* __restrict__ S1) {
    int tid = blockIdx.x * 256 + threadIdx.x;   // NL*NPIX exact
    int l = tid / NPIX, rem = tid - l * NPIX;
    int y = rem / WW, x1 = rem - y * WW;
    const float cs = (-0.5f / 9.0f) * L2E;
    const float* row = Qlm + l * NPIX + y * WW;
    float acc = 0.f;
    for (int x2 = 0; x2 < WW; x2++) {
        float d = (float)(x1 - x2);
        acc = fmaf(fexp2(cs * d * d), row[x2], acc);
    }
    S1[tid] = acc;
}

__global__ __launch_bounds__(256) void spatY(const float* __restrict__ S1, const float* __restrict__ norm_s,
                                             float* __restrict__ Sp) {
    int tid = blockIdx.x * 256 + threadIdx.x;
    int l = tid / NPIX, rem = tid - l * NPIX;
    int y1 = rem / WW, x = rem - y1 * WW;
    const float cs = (-0.5f / 9.0f) * L2E;
    float acc = 0.f;
    for (int y2 = 0; y2 < WW; y2++) {
        float d = (float)(y1 - y2);
        acc = fmaf(fexp2(cs * d * d), S1[l * NPIX + y2 * WW + x], acc);
    }
    Sp[tid] = acc * norm_s[rem];
}

// ---------- bilateral: out[l,i] = sum_j exp2(fi.fj' - si - sj) q[l,j], fused norm row ----------
// block: 256 threads, 2 pixels each (i0, i0+256) -> 512-pixel i-tile; blockIdx.y = j-chunk
__global__ __launch_bounds__(256) void bilatK(const float* __restrict__ Qt, const float* __restrict__ Fi,
                                              const float* __restrict__ Fj,
                                              float* __restrict__ part, int njc) {
    __shared__ __align__(16) float sQ[CH * QP];   // 3 KB
    __shared__ __align__(16) float sF[CH * 8];    // 1 KB
    int t = threadIdx.x;
    int i0 = blockIdx.x * 512 + t;
    int jc = blockIdx.y;

    float4 fA0 = *reinterpret_cast<const float4*>(Fi + (size_t)i0 * 8);
    float2 fB0 = *reinterpret_cast<const float2*>(Fi + (size_t)i0 * 8 + 4);
    float4 fA1 = *reinterpret_cast<const float4*>(Fi + (size_t)(i0 + 256) * 8);
    float2 fB1 = *reinterpret_cast<const float2*>(Fi + (size_t)(i0 + 256) * 8 + 4);

    float acc0[NL], acc1[NL], s0 = 0.f, s1 = 0.f;
    #pragma unroll
    for (int l = 0; l < NL; l++) { acc0[l] = 0.f; acc1[l] = 0.f; }

    int jbeg = jc * njc;
    for (int jb = jbeg; jb < jbeg + njc; jb += CH) {
        __syncthreads();
        if (t < 192) reinterpret_cast<float4*>(sQ)[t]       = reinterpret_cast<const float4*>(Qt + (size_t)jb * QP)[t];
        else         reinterpret_cast<float4*>(sF)[t - 192] = reinterpret_cast<const float4*>(Fj + (size_t)jb * 8)[t - 192];
        __syncthreads();
        #pragma unroll 4
        for (int j = 0; j < CH; j++) {
            float4 fa = *reinterpret_cast<const float4*>(sF + j * 8);
            float2 fb = *reinterpret_cast<const float2*>(sF + j * 8 + 4);
            float b0 = -(fB0.y + fb.y);
            float b1 = -(fB1.y + fb.y);
            b0 = fmaf(fa.x, fA0.x, b0);  b1 = fmaf(fa.x, fA1.x, b1);
            b0 = fmaf(fa.y, fA0.y, b0);  b1 = fmaf(fa.y, fA1.y, b1);
            b0 = fmaf(fa.z, fA0.z, b0);  b1 = fmaf(fa.z, fA1.z, b1);
            b0 = fmaf(fa.w, fA0.w, b0);  b1 = fmaf(fa.w, fA1.w, b1);
            b0 = fmaf(fb.x, fB0.x, b0);  b1 = fmaf(fb.x, fB1.x, b1);
            float k0 = fexp2(b0), k1 = fexp2(b1);
            s0 += k0; s1 += k1;
            const float* qr = sQ + j * QP;
            #pragma unroll
            for (int l = 0; l < NL; l++) {
                float q = qr[l];
                acc0[l] = fmaf(k0, q, acc0[l]);
                acc1[l] = fmaf(k1, q, acc1[l]);
            }
        }
    }
    float* p = part + (size_t)jc * 22 * NPIX + i0;
    #pragma unroll
    for (int l = 0; l < NL; l++) {
        p[(size_t)l * NPIX]       = acc0[l];
        p[(size_t)l * NPIX + 256] = acc1[l];
    }
    p[(size_t)21 * NPIX] = s0;
    p[(size_t)21 * NPIX + 256] = s1;
}

// ---------- reduce j-chunks (all 22 rows incl. denominator); norm applied in combK ----------
__global__ __launch_bounds__(256) void bredK(const float* __restrict__ part, float* __restrict__ Bl, int js) {
    int t = blockIdx.x * 256 + threadIdx.x;   // 22*NPIX = 202752 exact (792 blocks)
    float a = 0.f;
    for (int jc = 0; jc < js; jc++) a += part[(size_t)jc * 22 * NPIX + t];
    Bl[t] = a;
}

// ---------- combine: cur = Ms@Sp + Mb@(diag(1/denom) Bl) + unary ----------
__global__ __launch_bounds__(256) void combK(const float* __restrict__ Sp, const float* __restrict__ Bl,
                                             const float* __restrict__ Ms, const float* __restrict__ Mb,
                                             const float* __restrict__ unary, float* __restrict__ outp) {
    __shared__ float sMs[NL * NL], sMb[NL * NL];
    int t = threadIdx.x;
    for (int k = t; k < NL * NL; k += 256) { sMs[k] = Ms[k]; sMb[k] = Mb[k]; }
    __syncthreads();
    int i = blockIdx.x * 256 + t;
    if (i >= NPIX) return;
    float inv = 1.0f / (Bl[(size_t)21 * NPIX + i] + 1e-8f);
    float sp[NL], bl[NL];
    #pragma unroll
    for (int p = 0; p < NL; p++) { sp[p] = Sp[p * NPIX + i]; bl[p] = Bl[p * NPIX + i] * inv; }
    for (int l = 0; l < NL; l++) {
        float a = unary[l * NPIX + i];
        #pragma unroll
        for (int p = 0; p < NL; p++) {
            a = fmaf(sMs[l * NL + p], sp[p], a);
            a = fmaf(sMb[l * NL + p], bl[p], a);
        }
        outp[l * NPIX + i] = a;
    }
}

extern "C" void kernel_launch(void* const* d_in, const int* in_sizes, int n_in,
                              void* d_out, int out_size, void* d_ws, size_t ws_size,
                              hipStream_t stream) {
    const float* img   = (const float*)d_in[0];
    const float* logit = (const float*)d_in[1];
    const float* Wsm   = (const float*)d_in[2];
    const float* Wbm   = (const float*)d_in[3];
    const float* Cm    = (const float*)d_in[4];
    float* out = (float*)d_out;
    float* ws  = (float*)d_ws;

    // workspace layout (floats)
    float* Fi     = ws;                          // N*8      = 73728
    float* Fj     = Fi + NPIX * 8;               // N*8      = 73728
    float* Qt     = Fj + NPIX * 8;               // N*24     = 221184
    float* Qlm    = Qt + (size_t)NPIX * QP;      // L*N      = 193536
    float* S1     = Qlm + NL * NPIX;             // L*N      = 193536
    float* Sp     = S1 + NL * NPIX;              // L*N      = 193536
    float* Bl     = Sp + NL * NPIX;              // 22*N     = 202752
    float* norm_s = Bl + 22 * NPIX;              // N        = 9216
    float* Ms     = norm_s + NPIX;               // 441
    float* Mb     = Ms + 441;                    // 441
    float* part   = ws + 1162112;                // js*22*N (16B aligned)

    size_t baseB = 1162112ull * sizeof(float);
    int js = 32;
    while (js > 1 && baseB + (size_t)js * 22 * NPIX * sizeof(float) > ws_size) js >>= 1;
    int njc = NPIX / js;

    featK<<<36, 256, 0, stream>>>(img, Fi, Fj, norm_s);
    matK<<<1, 448, 0, stream>>>(Cm, Wsm, Wbm, Ms, Mb);
    for (int it = 0; it < 5; ++it) {
        const float* cur = (it == 0) ? logit : out;
        softmaxK<<<36, 256, 0, stream>>>(cur, Qt, Qlm);
        spatX<<<756, 256, 0, stream>>>(Qlm, S1);
        spatY<<<756, 256, 0, stream>>>(S1, norm_s, Sp);
        bilatK<<<dim3(18, js), 256, 0, stream>>>(Qt, Fi, Fj, part, njc);
        bredK<<<792, 256, 0, stream>>>(part, Bl, js);
        combK<<<36, 256, 0, stream>>>(Sp, Bl, Ms, Mb, logit, out);
    }
}